// Round 1
// baseline (4996.516 us; speedup 1.0000x reference)
//
#include <hip/hip_runtime.h>
#include <math.h>

static __device__ __forceinline__ float silu_f(float x){ return x / (1.f + expf(-x)); }

// ---------------- workspace layout (float offsets) ----------------
// stats region [0,8192):
//   bn_in: sc@0 sh@256 ; down: sc@512 sh@896 ; uc0 sc@1536 sh@1600 ;
//   uc1 sc@1664 sh@1728 ; fus0 sc@1792 sh@1856 ; fus1 sc@1920 sh@1984
#define OFF_FCAT   8192u        /* 9,830,400  (10,240,64,64) */
#define OFF_MFI    8192u        /* 2,621,440  reuse fcat region */
#define OFF_OUTS   2629632u     /* 2,621,440 */
#define OFF_DECIN  5251072u     /* 2,621,440 */
#define OFF_DOWN   9838592u     /* 3,932,160  (10,384,32,32) */
#define OFF_DECOUT 9838592u     /* 1,310,720  reuse down region */
#define OFF_UC0    11149312u    /* 655,360 */
#define OFF_UC1    11804672u    /* 655,360 */
#define OFF_TOK    13770752u    /* 7,864,320  (10240,12,64) */
#define OFF_FUS0   13770752u    /* 2,621,440  reuse tok region */
#define OFF_FUS1   16392192u    /* 2,621,440 */

// ---------------- K1: f = concat([high, features + tile(high,4)]) ----------------
__global__ __launch_bounds__(256) void k_fcat(const float* __restrict__ feat,
                                              const float* __restrict__ high,
                                              float* __restrict__ out){
    int idx = blockIdx.x*256 + threadIdx.x;          // total 9,830,400
    if (idx >= 9830400) return;
    int b   = idx / 983040;
    int rem = idx - b*983040;
    int c   = rem >> 12;
    int hw  = rem & 4095;
    float v;
    if (c < 48){
        v = high[((size_t)b*48 + c)*4096 + hw];
    } else {
        int c2 = c - 48;
        v = feat[((size_t)b*192 + c2)*4096 + hw] + high[((size_t)b*48 + (c2 % 48))*4096 + hw];
    }
    out[idx] = v;
}

// ---------------- generic BN stats: one block per channel ----------------
__global__ __launch_bounds__(256) void k_bn_stats(const float* __restrict__ x,
                                                  const float* __restrict__ g,
                                                  const float* __restrict__ b,
                                                  float* __restrict__ scale,
                                                  float* __restrict__ shift,
                                                  int C, int hwshift, int N){
    int c = blockIdx.x;
    int HW = 1 << hwshift;
    int total = N << hwshift;
    float s = 0.f, s2 = 0.f;
    for (int i = threadIdx.x; i < total; i += 256){
        int n  = i >> hwshift;
        int hw = i & (HW - 1);
        float v = x[((size_t)n*C + c)*HW + hw];
        s += v; s2 = fmaf(v, v, s2);
    }
    __shared__ float rs[256], rq[256];
    rs[threadIdx.x] = s; rq[threadIdx.x] = s2;
    __syncthreads();
    for (int off = 128; off; off >>= 1){
        if (threadIdx.x < off){ rs[threadIdx.x] += rs[threadIdx.x+off]; rq[threadIdx.x] += rq[threadIdx.x+off]; }
        __syncthreads();
    }
    if (threadIdx.x == 0){
        float inv = 1.f / (float)total;
        float m   = rs[0]*inv;
        float var = rq[0]*inv - m*m;
        if (var < 0.f) var = 0.f;
        float sc = g[c] * rsqrtf(var + 1e-5f);
        scale[c] = sc;
        shift[c] = b[c] - m*sc;
    }
}

// ---------------- in-place affine + SiLU ----------------
__global__ __launch_bounds__(256) void k_affine_silu(float* __restrict__ x,
                                                     const float* __restrict__ scale,
                                                     const float* __restrict__ shift,
                                                     int C, int hwshift, int total){
    int idx = blockIdx.x*256 + threadIdx.x;
    if (idx >= total) return;
    int c = (idx >> hwshift) % C;
    float v = fmaf(x[idx], scale[c], shift[c]);
    x[idx] = silu_f(v);
}

// ---------------- down conv: 3x3 s2 g12, BN(input) fused ----------------
__global__ __launch_bounds__(256) void k_down(const float* __restrict__ fcat,
                                              const float* __restrict__ w,
                                              const float* __restrict__ sc,
                                              const float* __restrict__ sh,
                                              float* __restrict__ out){
    int idx = blockIdx.x*256 + threadIdx.x;          // 3,932,160 = 10*384*1024
    if (idx >= 3932160) return;
    int b   = idx / 393216;
    int rem = idx - b*393216;
    int o   = rem >> 10;
    int hw  = rem & 1023;
    int oh = hw >> 5, ow = hw & 31;
    int ibase = (o >> 5) * 20;                        // group = o/32, 20 in-ch per group
    const float* wt = w + (size_t)o*180;              // 20*9
    float acc = 0.f;
    for (int ci = 0; ci < 20; ++ci){
        int c = ibase + ci;
        const float* inp = fcat + ((size_t)b*240 + c)*4096;
        float s = sc[c], t = sh[c];
        const float* wr = wt + ci*9;
        #pragma unroll
        for (int kh = 0; kh < 3; ++kh){
            int ih = oh*2 + kh - 1;
            if (ih < 0 || ih >= 64) continue;
            #pragma unroll
            for (int kw = 0; kw < 3; ++kw){
                int iw = ow*2 + kw - 1;
                if (iw < 0 || iw >= 64) continue;
                acc += fmaf(inp[ih*64 + iw], s, t) * wr[kh*3 + kw];
            }
        }
    }
    out[idx] = acc;
}

// ---------------- emb conv: 3x3 g12 + bias, writes token layout ----------------
__global__ __launch_bounds__(256) void k_emb(const float* __restrict__ down_act,
                                             const float* __restrict__ w,
                                             const float* __restrict__ bias,
                                             float* __restrict__ tok){
    int idx = blockIdx.x*256 + threadIdx.x;          // 7,864,320 = 10*768*1024
    if (idx >= 7864320) return;
    int b   = idx / 786432;
    int rem = idx - b*786432;
    int c   = rem >> 10;
    int hw  = rem & 1023;
    int oh = hw >> 5, ow = hw & 31;
    int ibase = (c >> 6) * 32;                        // group = c/64, 32 in-ch
    const float* wt = w + (size_t)c*288;              // 32*9
    float acc = bias[c];
    for (int ci = 0; ci < 32; ++ci){
        const float* inp = down_act + ((size_t)b*384 + ibase + ci)*1024;
        const float* wr = wt + ci*9;
        #pragma unroll
        for (int kh = 0; kh < 3; ++kh){
            int ih = oh + kh - 1;
            if (ih < 0 || ih >= 32) continue;
            #pragma unroll
            for (int kw = 0; kw < 3; ++kw){
                int iw = ow + kw - 1;
                if (iw < 0 || iw >= 32) continue;
                acc = fmaf(inp[ih*32 + iw], wr[kh*3 + kw], acc);
            }
        }
    }
    tok[((size_t)(b*1024 + hw))*768 + c] = acc;
}

// ---------------- wave-64 reductions ----------------
static __device__ __forceinline__ float wsum64(float v){
    #pragma unroll
    for (int m = 32; m; m >>= 1) v += __shfl_xor(v, m, 64);
    return v;
}

// ---------------- LN1 (in-place) + mfi extraction ----------------
__global__ __launch_bounds__(256) void k_ln1(float* __restrict__ tok,
                                             float* __restrict__ mfi,
                                             const float* __restrict__ g,
                                             const float* __restrict__ bta){
    int row = blockIdx.x*4 + (threadIdx.x >> 6);     // 122,880 rows (token*12+s)
    int d   = threadIdx.x & 63;
    int token = row / 12, s = row - token*12;
    size_t base = (size_t)row * 64;
    float v = tok[base + d];
    if (s >= 8) mfi[(size_t)token*256 + (s - 8)*64 + d] = v;
    float m  = wsum64(v) * (1.f/64.f);
    float dv = v - m;
    float var = wsum64(dv*dv) * (1.f/64.f);
    tok[base + d] = dv * rsqrtf(var + 1e-5f) * g[d] + bta[d];
}

// ---------------- fused Mamba: 3 chunks, state in LDS ----------------
__global__ __launch_bounds__(256) void k_mamba(const float* __restrict__ tok,
                                               const float* __restrict__ in_w,    // (3,256,64)
                                               const float* __restrict__ conv_w,  // (3,128)
                                               const float* __restrict__ conv_b,
                                               const float* __restrict__ xproj_w, // (3,64,128)
                                               const float* __restrict__ dt_w,    // (3,128,32)
                                               const float* __restrict__ dt_b,
                                               const float* __restrict__ A_log,   // (3,128,16)
                                               const float* __restrict__ Dp,      // (3,128)
                                               const float* __restrict__ out_w,   // (3,64,128)
                                               float* __restrict__ outs){         // (10240,4,64)
    int token = blockIdx.x;
    int tid = threadIdx.x;
    __shared__ float st[2048];
    __shared__ float A[2048];
    __shared__ float xs[64];
    __shared__ float xi[128];
    __shared__ float siluz[128];
    __shared__ float xdb[64];
    __shared__ float dtv[128];
    __shared__ float yz[512];

    for (int i = tid; i < 2048; i += 256) st[i] = 0.f;
    const float* tokrow = tok + (size_t)token * 768;

    int off = 0;
    for (int chunk = 0; chunk < 3; ++chunk){
        const float* iw = in_w    + (size_t)chunk*256*64;
        const float* xw = xproj_w + (size_t)chunk*64*128;
        const float* dw = dt_w    + (size_t)chunk*128*32;
        const float* ow = out_w   + (size_t)chunk*64*128;
        for (int i = tid; i < 2048; i += 256) A[i] = -expf(A_log[(size_t)chunk*2048 + i]);
        bool last = (chunk == 2);

        for (int t = 0; t < 4; ++t){
            __syncthreads();
            if (tid < 64) xs[tid] = tokrow[(off + t)*64 + tid];
            __syncthreads();
            // in-proj: 256 outputs (xi + z) on last chunk, 128 (xi only) otherwise
            if (last || tid < 128){
                const float* wrow = iw + (size_t)tid*64;
                float acc = 0.f;
                #pragma unroll
                for (int d = 0; d < 64; ++d) acc = fmaf(xs[d], wrow[d], acc);
                if (tid < 128){
                    float v = fmaf(acc, conv_w[chunk*128 + tid], conv_b[chunk*128 + tid]);
                    xi[tid] = silu_f(v);
                } else {
                    siluz[tid - 128] = silu_f(acc);
                }
            }
            __syncthreads();
            if (tid < 64){
                const float* wrow = xw + (size_t)tid*128;
                float acc = 0.f;
                #pragma unroll
                for (int d = 0; d < 128; ++d) acc = fmaf(xi[d], wrow[d], acc);
                xdb[tid] = acc;
            }
            __syncthreads();
            if (tid < 128){
                const float* wrow = dw + (size_t)tid*32;
                float acc = dt_b[chunk*128 + tid];
                #pragma unroll
                for (int r = 0; r < 32; ++r) acc = fmaf(xdb[r], wrow[r], acc);
                dtv[tid] = (acc > 20.f) ? acc : log1pf(expf(acc));
            }
            __syncthreads();
            {   // state update: thread -> (ch = tid>>1, 8 states)
                int ch = tid >> 1, n0 = (tid & 1) * 8;
                float dtc = dtv[ch];
                float dx  = dtc * xi[ch];
                #pragma unroll
                for (int k = 0; k < 8; ++k){
                    int n = n0 + k;
                    int sidx = ch*16 + n;
                    st[sidx] = fmaf(st[sidx], expf(dtc * A[sidx]), dx * xdb[32 + n]);
                }
            }
            __syncthreads();
            if (last && tid < 128){
                float acc = 0.f;
                #pragma unroll
                for (int n = 0; n < 16; ++n) acc = fmaf(st[tid*16 + n], xdb[48 + n], acc);
                acc = fmaf(Dp[chunk*128 + tid], xi[tid], acc);
                yz[t*128 + tid] = acc * siluz[tid];
            }
        }
        if (last){
            __syncthreads();
            int l = tid >> 6, e = tid & 63;
            const float* wrow = ow + (size_t)e*128;
            float acc = 0.f;
            #pragma unroll
            for (int ch = 0; ch < 128; ++ch) acc = fmaf(yz[l*128 + ch], wrow[ch], acc);
            outs[(size_t)token*256 + l*64 + e] = acc;
        }
        off += 4;
    }
}

// ---------------- LN2 + transpose to (10,256,32,32) ----------------
__global__ __launch_bounds__(256) void k_ln2t(const float* __restrict__ mfi,
                                              const float* __restrict__ outs,
                                              const float* __restrict__ g,
                                              const float* __restrict__ bta,
                                              float* __restrict__ dec_in){
    int row = blockIdx.x*4 + (threadIdx.x >> 6);     // 40,960 rows (token*4+l)
    int d   = threadIdx.x & 63;
    int token = row >> 2, l = row & 3;
    float v = mfi[(size_t)row*64 + d] + outs[(size_t)row*64 + d];
    float m  = wsum64(v) * (1.f/64.f);
    float dv = v - m;
    float var = wsum64(dv*dv) * (1.f/64.f);
    float r = dv * rsqrtf(var + 1e-5f) * g[d] + bta[d];
    int b = token >> 10, hw = token & 1023;
    dec_in[(size_t)b*262144 + (size_t)(l*64 + d)*1024 + hw] = r;
}

// ---------------- dec conv: 3x3 g4 + bias ----------------
__global__ __launch_bounds__(256) void k_dec(const float* __restrict__ dec_in,
                                             const float* __restrict__ w,
                                             const float* __restrict__ bias,
                                             float* __restrict__ out){
    int idx = blockIdx.x*256 + threadIdx.x;          // 1,310,720 = 10*128*1024
    if (idx >= 1310720) return;
    int b   = idx / 131072;
    int rem = idx - b*131072;
    int o   = rem >> 10;
    int hw  = rem & 1023;
    int oh = hw >> 5, ow = hw & 31;
    int ibase = (o >> 5) * 64;
    const float* wt = w + (size_t)o*576;             // 64*9
    float acc = bias[o];
    for (int ci = 0; ci < 64; ++ci){
        const float* inp = dec_in + ((size_t)b*256 + ibase + ci)*1024;
        const float* wr = wt + ci*9;
        #pragma unroll
        for (int kh = 0; kh < 3; ++kh){
            int ih = oh + kh - 1;
            if (ih < 0 || ih >= 32) continue;
            #pragma unroll
            for (int kw = 0; kw < 3; ++kw){
                int iw = ow + kw - 1;
                if (iw < 0 || iw >= 32) continue;
                acc = fmaf(inp[ih*32 + iw], wr[kh*3 + kw], acc);
            }
        }
    }
    out[idx] = acc;
}

// ---------------- up 1x1 convs (both branches), at 32x32 ----------------
__global__ __launch_bounds__(256) void k_up(const float* __restrict__ dec_out,
                                            const float* __restrict__ w0,
                                            const float* __restrict__ w1,
                                            float* __restrict__ uc0,
                                            float* __restrict__ uc1){
    int idx = blockIdx.x*256 + threadIdx.x;          // 1,310,720 = 2*10*64*1024
    if (idx >= 1310720) return;
    int r = idx >= 655360;
    int j = idx - r*655360;
    int b   = j / 65536;
    int rem = j - b*65536;
    int o   = rem >> 10;
    int hw  = rem & 1023;
    const float* w = r ? w1 : w0;
    const float* in = dec_out + (size_t)b*131072 + (size_t)(r*64)*1024 + hw;
    float acc = 0.f;
    #pragma unroll
    for (int i = 0; i < 64; ++i) acc = fmaf(in[(size_t)i*1024], w[o*64 + i], acc);
    (r ? uc1 : uc0)[j] = acc;
}

// ---------------- fuse conv: 3x3, input = [upsampled uc_act(64) ; fid(64)] ----------------
__global__ __launch_bounds__(256) void k_fus(const float* __restrict__ uc_act,
                                             const float* __restrict__ fid,
                                             const float* __restrict__ w,
                                             const float* __restrict__ bias,
                                             float* __restrict__ out){
    int idx = blockIdx.x*256 + threadIdx.x;          // 2,621,440 = 10*64*4096
    if (idx >= 2621440) return;
    int b   = idx >> 18;
    int rem = idx & 262143;
    int o   = rem >> 12;
    int hw  = rem & 4095;
    int oh = hw >> 6, ow = hw & 63;
    const float* wt = w + (size_t)o*1152;            // 128*9
    float acc = bias[o];
    for (int i = 0; i < 64; ++i){
        const float* up = uc_act + ((size_t)b*64 + i)*1024;
        const float* wr = wt + i*9;
        #pragma unroll
        for (int kh = 0; kh < 3; ++kh){
            int ih = oh + kh - 1;
            if (ih < 0 || ih >= 64) continue;
            const float* uprow = up + (ih >> 1)*32;
            #pragma unroll
            for (int kw = 0; kw < 3; ++kw){
                int iw = ow + kw - 1;
                if (iw < 0 || iw >= 64) continue;
                acc = fmaf(uprow[iw >> 1], wr[kh*3 + kw], acc);
            }
        }
    }
    for (int i = 0; i < 64; ++i){
        const float* fp = fid + ((size_t)b*64 + i)*4096;
        const float* wr = wt + (64 + i)*9;
        #pragma unroll
        for (int kh = 0; kh < 3; ++kh){
            int ih = oh + kh - 1;
            if (ih < 0 || ih >= 64) continue;
            #pragma unroll
            for (int kw = 0; kw < 3; ++kw){
                int iw = ow + kw - 1;
                if (iw < 0 || iw >= 64) continue;
                acc = fmaf(fp[ih*64 + iw], wr[kh*3 + kw], acc);
            }
        }
    }
    out[idx] = acc;
}

// ---------------- final 1x1 conv + SiLU ----------------
__global__ __launch_bounds__(256) void k_final(const float* __restrict__ f0,
                                               const float* __restrict__ f1,
                                               const float* __restrict__ w,
                                               const float* __restrict__ bias,
                                               float* __restrict__ out){
    int idx = blockIdx.x*256 + threadIdx.x;          // 2,621,440 = 10*64*4096
    if (idx >= 2621440) return;
    int b   = idx >> 18;
    int rem = idx & 262143;
    int o   = rem >> 12;
    int hw  = rem & 4095;
    const float* p0 = f0 + (size_t)b*262144 + hw;
    const float* p1 = f1 + (size_t)b*262144 + hw;
    const float* w0 = w + o*128;
    float acc = bias[o];
    #pragma unroll
    for (int i = 0; i < 64; ++i) acc = fmaf(p0[(size_t)i*4096], w0[i], acc);
    #pragma unroll
    for (int i = 0; i < 64; ++i) acc = fmaf(p1[(size_t)i*4096], w0[64 + i], acc);
    out[idx] = silu_f(acc);
}

extern "C" void kernel_launch(void* const* d_in, const int* in_sizes, int n_in,
                              void* d_out, int out_size, void* d_ws, size_t ws_size,
                              hipStream_t stream) {
    const float* features = (const float*)d_in[0];
    const float* high     = (const float*)d_in[1];
    const float* fid0     = (const float*)d_in[2];
    const float* fid1     = (const float*)d_in[3];
    const float* bn_in_g  = (const float*)d_in[4];
    const float* bn_in_b  = (const float*)d_in[5];
    const float* down_w   = (const float*)d_in[6];
    const float* down_bn_g= (const float*)d_in[7];
    const float* down_bn_b= (const float*)d_in[8];
    const float* emb_w    = (const float*)d_in[9];
    const float* emb_b    = (const float*)d_in[10];
    const float* ln1_g    = (const float*)d_in[11];
    const float* ln1_b    = (const float*)d_in[12];
    const float* m_in_w   = (const float*)d_in[13];
    const float* m_conv_w = (const float*)d_in[14];
    const float* m_conv_b = (const float*)d_in[15];
    const float* m_xproj_w= (const float*)d_in[16];
    const float* m_dt_w   = (const float*)d_in[17];
    const float* m_dt_b   = (const float*)d_in[18];
    const float* m_A_log  = (const float*)d_in[19];
    const float* m_D      = (const float*)d_in[20];
    const float* m_out_w  = (const float*)d_in[21];
    const float* ln2_g    = (const float*)d_in[22];
    const float* ln2_b    = (const float*)d_in[23];
    const float* dec_w    = (const float*)d_in[24];
    const float* dec_b    = (const float*)d_in[25];
    const float* up0_w    = (const float*)d_in[26];
    const float* up0_bn_g = (const float*)d_in[27];
    const float* up0_bn_b = (const float*)d_in[28];
    const float* up1_w    = (const float*)d_in[29];
    const float* up1_bn_g = (const float*)d_in[30];
    const float* up1_bn_b = (const float*)d_in[31];
    const float* fus0_w   = (const float*)d_in[32];
    const float* fus0_b   = (const float*)d_in[33];
    const float* fus0_bn_g= (const float*)d_in[34];
    const float* fus0_bn_b= (const float*)d_in[35];
    const float* fus1_w   = (const float*)d_in[36];
    const float* fus1_b   = (const float*)d_in[37];
    const float* fus1_bn_g= (const float*)d_in[38];
    const float* fus1_bn_b= (const float*)d_in[39];
    const float* outf_w   = (const float*)d_in[40];
    const float* outf_b   = (const float*)d_in[41];

    float* ws = (float*)d_ws;
    float* out = (float*)d_out;

    float* st_in_sc  = ws + 0;    float* st_in_sh  = ws + 256;
    float* st_dn_sc  = ws + 512;  float* st_dn_sh  = ws + 896;
    float* st_u0_sc  = ws + 1536; float* st_u0_sh  = ws + 1600;
    float* st_u1_sc  = ws + 1664; float* st_u1_sh  = ws + 1728;
    float* st_f0_sc  = ws + 1792; float* st_f0_sh  = ws + 1856;
    float* st_f1_sc  = ws + 1920; float* st_f1_sh  = ws + 1984;

    float* fcat   = ws + OFF_FCAT;
    float* mfi    = ws + OFF_MFI;
    float* outs   = ws + OFF_OUTS;
    float* dec_in = ws + OFF_DECIN;
    float* down   = ws + OFF_DOWN;
    float* dec_out= ws + OFF_DECOUT;
    float* uc0    = ws + OFF_UC0;
    float* uc1    = ws + OFF_UC1;
    float* tok    = ws + OFF_TOK;
    float* fus0   = ws + OFF_FUS0;
    float* fus1   = ws + OFF_FUS1;

    // 1. build concat input
    k_fcat<<<38400, 256, 0, stream>>>(features, high, fcat);
    // 2. BN stats on fcat (240 ch, 64x64, N=10)
    k_bn_stats<<<240, 256, 0, stream>>>(fcat, bn_in_g, bn_in_b, st_in_sc, st_in_sh, 240, 12, 10);
    // 3. down conv (affine fused on reads)
    k_down<<<15360, 256, 0, stream>>>(fcat, down_w, st_in_sc, st_in_sh, down);
    // 4. BN stats on down (384 ch, 32x32, N=10)
    k_bn_stats<<<384, 256, 0, stream>>>(down, down_bn_g, down_bn_b, st_dn_sc, st_dn_sh, 384, 10, 10);
    // 5. in-place BN+SiLU
    k_affine_silu<<<15360, 256, 0, stream>>>(down, st_dn_sc, st_dn_sh, 384, 10, 3932160);
    // 6. emb conv -> token layout
    k_emb<<<30720, 256, 0, stream>>>(down, emb_w, emb_b, tok);
    // 7. LN1 in-place + mfi
    k_ln1<<<30720, 256, 0, stream>>>(tok, mfi, ln1_g, ln1_b);
    // 8. fused mamba (3 chunks)
    k_mamba<<<10240, 256, 0, stream>>>(tok, m_in_w, m_conv_w, m_conv_b, m_xproj_w,
                                       m_dt_w, m_dt_b, m_A_log, m_D, m_out_w, outs);
    // 9. LN2 + transpose
    k_ln2t<<<10240, 256, 0, stream>>>(mfi, outs, ln2_g, ln2_b, dec_in);
    // 10. dec conv
    k_dec<<<5120, 256, 0, stream>>>(dec_in, dec_w, dec_b, dec_out);
    // 11. up 1x1 convs at 32x32
    k_up<<<5120, 256, 0, stream>>>(dec_out, up0_w, up1_w, uc0, uc1);
    // 12. BN stats + activate uc0/uc1 (stats on upsampled map == stats at 32x32)
    k_bn_stats<<<64, 256, 0, stream>>>(uc0, up0_bn_g, up0_bn_b, st_u0_sc, st_u0_sh, 64, 10, 10);
    k_bn_stats<<<64, 256, 0, stream>>>(uc1, up1_bn_g, up1_bn_b, st_u1_sc, st_u1_sh, 64, 10, 10);
    k_affine_silu<<<2560, 256, 0, stream>>>(uc0, st_u0_sc, st_u0_sh, 64, 10, 655360);
    k_affine_silu<<<2560, 256, 0, stream>>>(uc1, st_u1_sc, st_u1_sh, 64, 10, 655360);
    // 13. fuse convs
    k_fus<<<10240, 256, 0, stream>>>(uc0, fid0, fus0_w, fus0_b, fus0);
    k_fus<<<10240, 256, 0, stream>>>(uc1, fid1, fus1_w, fus1_b, fus1);
    // 14. BN stats + activate fus0/fus1
    k_bn_stats<<<64, 256, 0, stream>>>(fus0, fus0_bn_g, fus0_bn_b, st_f0_sc, st_f0_sh, 64, 12, 10);
    k_bn_stats<<<64, 256, 0, stream>>>(fus1, fus1_bn_g, fus1_bn_b, st_f1_sc, st_f1_sh, 64, 12, 10);
    k_affine_silu<<<10240, 256, 0, stream>>>(fus0, st_f0_sc, st_f0_sh, 64, 12, 2621440);
    k_affine_silu<<<10240, 256, 0, stream>>>(fus1, st_f1_sc, st_f1_sh, 64, 12, 2621440);
    // 15. final 1x1 + SiLU -> d_out
    k_final<<<10240, 256, 0, stream>>>(fus0, fus1, outf_w, outf_b, out);
}